// Round 2
// baseline (2344.509 us; speedup 1.0000x reference)
//
#include <hip/hip_runtime.h>
#include <stdint.h>

// Problem constants (from reference)
#define N_ENTS  100000
#define N_RELS  16
#define DIM     128
#define NB      4
#define NEDGE   640000
#define BATCH   1024
#define NNEG    64
#define BN_EPS  1e-5f

// converted-parameter buffer layout (ushort offsets)
#define P_REL    0        // [16][128]
#define P_BASES  2048     // [2][4][128][128]
#define P_COEFF  133120   // [2][16][4]
#define P_WSL    133248   // [2][128][128]
#define P_BSL    166016   // [2][128]
#define P_GAMMA  166272   // [2][128]
#define P_BETA   166528   // [2][128]
#define P_TOTAL  166784

// bf16 helpers (internal canonical format = raw ushort bf16)
__device__ __forceinline__ float bf2f(unsigned short u) {
    return __uint_as_float(((unsigned int)u) << 16);
}
__device__ __forceinline__ float bflo(unsigned int u) { return __uint_as_float(u << 16); }
__device__ __forceinline__ float bfhi(unsigned int u) { return __uint_as_float(u & 0xffff0000u); }
__device__ __forceinline__ unsigned short f2bf(float f) {
    unsigned int x = __float_as_uint(f);
    x += 0x7fffu + ((x >> 16) & 1u);   // round-to-nearest-even
    return (unsigned short)(x >> 16);
}
__device__ __forceinline__ unsigned int pack2(float a, float b) {
    return (unsigned int)f2bf(a) | ((unsigned int)f2bf(b) << 16);
}

// ---------------- dtype detection ----------------
// bf16 storage: both 16-bit halves of each word have exponent in a narrow band
// (entity_table ~ N(0,0.02)). fp32 storage: low half is random mantissa bits.
__device__ __forceinline__ int bf16_like(unsigned int h) {
    unsigned int m = h & 0x7FFFu;
    return (m == 0u) || (m >= 0x2D00u && m < 0x4400u);  // exp in [90,136) or zero
}
__global__ __launch_bounds__(256) void k_detect(const unsigned int* __restrict__ ent,
                                                int* __restrict__ flag) {
    __shared__ int cnt[256];
    unsigned int u = ent[threadIdx.x];
    cnt[threadIdx.x] = bf16_like(u & 0xFFFFu) & bf16_like(u >> 16);
    __syncthreads();
    for (int s = 128; s > 0; s >>= 1) {
        if (threadIdx.x < s) cnt[threadIdx.x] += cnt[threadIdx.x + s];
        __syncthreads();
    }
    if (threadIdx.x == 0) flag[0] = (cnt[0] >= 140) ? 1 : 0;
}

// ---------------- convert input (fp32 or bf16) -> canonical bf16 ----------------
__global__ __launch_bounds__(256) void k_conv(const void* __restrict__ src,
                                              unsigned short* __restrict__ dst,
                                              int n, const int* __restrict__ flag) {
    const int i = blockIdx.x * 256 + threadIdx.x;
    if (i >= n) return;
    if (flag[0]) {
        dst[i] = ((const unsigned short*)src)[i];
    } else {
        dst[i] = f2bf(((const float*)src)[i]);
    }
}

// ---------------- degree ----------------
__global__ __launch_bounds__(256) void k_deg(const int* __restrict__ dst, float* __restrict__ deg) {
    int e = blockIdx.x * 256 + threadIdx.x;
    if (e < NEDGE) atomicAdd(&deg[dst[e]], 1.0f);
}

// ---------------- fused node GEMM: out = x@w_sl + b_sl (fp32); z[n][f*4+b] = x@bases[b] (bf16) ----
// 1 wave per node row; lane handles f0=2*lane, f1=2*lane+1.
__global__ __launch_bounds__(256) void k_node_gemm(
    const unsigned short* __restrict__ x,      // [N][128] bf16
    const unsigned short* __restrict__ w_sl,   // [128][128] bf16 (layer slice)
    const unsigned short* __restrict__ b_sl,   // [128]
    const unsigned short* __restrict__ bases,  // [4][128][128]
    float* __restrict__ out,                   // [N][128] fp32
    unsigned short* __restrict__ z)            // [N][512] bf16, layout [n][f*4+b]
{
    __shared__ float xs[4][DIM];
    const int wave = threadIdx.x >> 6, lane = threadIdx.x & 63;
    const int n = blockIdx.x * 4 + wave;   // grid is exact: N_ENTS/4 blocks

    const unsigned int xr = ((const unsigned int*)(x + (size_t)n * DIM))[lane];
    xs[wave][2 * lane]     = bflo(xr);
    xs[wave][2 * lane + 1] = bfhi(xr);
    __syncthreads();

    float a0 = 0.f, a1 = 0.f;
    float z0[NB] = {0, 0, 0, 0}, z1[NB] = {0, 0, 0, 0};
    const unsigned int* w32 = (const unsigned int*)w_sl;
    const unsigned int* b32 = (const unsigned int*)bases;

#pragma unroll 4
    for (int d = 0; d < DIM; ++d) {
        const float xv = xs[wave][d];
        const unsigned int w = w32[d * 64 + lane];
        a0 = fmaf(xv, bflo(w), a0);
        a1 = fmaf(xv, bfhi(w), a1);
#pragma unroll
        for (int b = 0; b < NB; ++b) {
            const unsigned int bb = b32[b * 8192 + d * 64 + lane];
            z0[b] = fmaf(xv, bflo(bb), z0[b]);
            z1[b] = fmaf(xv, bfhi(bb), z1[b]);
        }
    }
    const int f0 = 2 * lane;
    float2 o;
    o.x = a0 + bf2f(b_sl[f0]);
    o.y = a1 + bf2f(b_sl[f0 + 1]);
    *(float2*)(out + (size_t)n * DIM + f0) = o;

    uint4 q;
    q.x = pack2(z0[0], z0[1]);
    q.y = pack2(z0[2], z0[3]);
    q.z = pack2(z1[0], z1[1]);
    q.w = pack2(z1[2], z1[3]);
    *(uint4*)(z + (size_t)n * 512 + (size_t)f0 * 4) = q;
}

// ---------------- edge scatter: out[dst] += sum_b c[et,b] * z_b[src] ----------------
__global__ __launch_bounds__(256) void k_edge(
    const int* __restrict__ src, const int* __restrict__ dst, const int* __restrict__ et,
    const unsigned short* __restrict__ coeffs,  // [16][4] bf16 (layer slice)
    const unsigned short* __restrict__ z,       // [N][512]
    float* __restrict__ out)                    // [N][128]
{
    const int wave = threadIdx.x >> 6, lane = threadIdx.x & 63;
    const int e = blockIdx.x * 4 + wave;   // grid exact: NEDGE/4
    const int s = src[e], d = dst[e], r = et[e];
    const uint2 cc = *(const uint2*)(coeffs + r * 4);
    const float c0 = bflo(cc.x), c1 = bfhi(cc.x), c2 = bflo(cc.y), c3 = bfhi(cc.y);
    const uint4 v = *(const uint4*)(z + (size_t)s * 512 + (size_t)lane * 8);
    const float m0 = c0 * bflo(v.x) + c1 * bfhi(v.x) + c2 * bflo(v.y) + c3 * bfhi(v.y);
    const float m1 = c0 * bflo(v.z) + c1 * bfhi(v.z) + c2 * bflo(v.w) + c3 * bfhi(v.w);
    float* op = out + (size_t)d * DIM + 2 * lane;
    atomicAdd(op, m0);
    atomicAdd(op + 1, m1);
}

// ---------------- divide by degree + BN batch stats ----------------
__global__ __launch_bounds__(256) void k_finstats(
    float* __restrict__ out, const float* __restrict__ deg, float* __restrict__ stats /* [2*128] */)
{
    const int f = threadIdx.x & 127;
    const int half = threadIdx.x >> 7;
    const int base = blockIdx.x * 128;
    float s = 0.f, ss = 0.f;
    for (int r = half; r < 128; r += 2) {
        const int n = base + r;
        if (n >= N_ENTS) break;
        const float dg = fmaxf(deg[n], 1.0f);
        const float o = out[(size_t)n * DIM + f] / dg;
        out[(size_t)n * DIM + f] = o;
        s += o;
        ss += o * o;
    }
    __shared__ float ls[256], lss[256];
    ls[threadIdx.x] = s;
    lss[threadIdx.x] = ss;
    __syncthreads();
    if (half == 0) {
        atomicAdd(&stats[f], ls[f] + ls[f + 128]);
        atomicAdd(&stats[DIM + f], lss[f] + lss[f + 128]);
    }
}

// ---------------- BN apply + ReLU -> bf16 x_next ----------------
__global__ __launch_bounds__(256) void k_bn(
    const float* __restrict__ out, const float* __restrict__ stats,
    const unsigned short* __restrict__ gamma, const unsigned short* __restrict__ beta,
    unsigned short* __restrict__ xnext)
{
    const long long i = (long long)blockIdx.x * 256 + threadIdx.x;  // pair index
    if (i >= (long long)N_ENTS * 64) return;
    const int f0 = (int)((i & 63) * 2);
    const float inv_n = 1.0f / (float)N_ENTS;
    const float mu0 = stats[f0] * inv_n, mu1 = stats[f0 + 1] * inv_n;
    const float v0 = stats[DIM + f0] * inv_n - mu0 * mu0;
    const float v1 = stats[DIM + f0 + 1] * inv_n - mu1 * mu1;
    const float g0 = bf2f(gamma[f0]) * rsqrtf(v0 + BN_EPS);
    const float g1 = bf2f(gamma[f0 + 1]) * rsqrtf(v1 + BN_EPS);
    const float2 o = *(const float2*)(out + i * 2);
    float r0 = (o.x - mu0) * g0 + bf2f(beta[f0]);
    float r1 = (o.y - mu1) * g1 + bf2f(beta[f0 + 1]);
    r0 = fmaxf(r0, 0.f);
    r1 = fmaxf(r1, 0.f);
    ((unsigned int*)xnext)[i] = pack2(r0, r1);
}

// ---------------- scoring ----------------
__global__ __launch_bounds__(256) void k_hr(
    const int* __restrict__ head, const int* __restrict__ rel,
    const unsigned short* __restrict__ ent, const unsigned short* __restrict__ rtab,
    float* __restrict__ hr)
{
    const int wave = threadIdx.x >> 6, lane = threadIdx.x & 63;
    const int i = blockIdx.x * 4 + wave;   // exact: BATCH/4
    const int h = head[i], r = rel[i];
    const unsigned int hv = ((const unsigned int*)(ent + (size_t)h * DIM))[lane];
    const unsigned int rv = ((const unsigned int*)(rtab + (size_t)r * DIM))[lane];
    float2 o;
    o.x = bflo(hv) + bflo(rv);
    o.y = bfhi(hv) + bfhi(rv);
    *(float2*)(hr + (size_t)i * DIM + 2 * lane) = o;
}

// score kernel: dist over tails idx[w]; writes out[obase + w] in detected dtype
__global__ __launch_bounds__(256) void k_score(
    const int* __restrict__ idx, const float* __restrict__ hr,
    const unsigned short* __restrict__ ent, void* __restrict__ outp,
    const int* __restrict__ flag, int obase, int hr_shift)
{
    const int wave = threadIdx.x >> 6, lane = threadIdx.x & 63;
    const int w = blockIdx.x * 4 + wave;
    const int i = w >> hr_shift;           // hr row
    const int t = idx[w];
    const float2 h = *(const float2*)(hr + (size_t)i * DIM + 2 * lane);
    const unsigned int tv = ((const unsigned int*)(ent + (size_t)t * DIM))[lane];
    const float d0 = h.x - bflo(tv), d1 = h.y - bfhi(tv);
    float s = d0 * d0 + d1 * d1;
#pragma unroll
    for (int m = 32; m >= 1; m >>= 1) s += __shfl_xor(s, m, 64);
    if (lane == 0) {
        const float v = -sqrtf(s);
        if (flag[0]) ((unsigned short*)outp)[obase + w] = f2bf(v);
        else         ((float*)outp)[obase + w] = v;
    }
}

extern "C" void kernel_launch(void* const* d_in, const int* in_sizes, int n_in,
                              void* d_out, int out_size, void* d_ws, size_t ws_size,
                              hipStream_t stream)
{
    const int* head = (const int*)d_in[0];
    const int* rel  = (const int*)d_in[1];
    const int* tail = (const int*)d_in[2];
    const int* negi = (const int*)d_in[3];
    const int* eidx = (const int*)d_in[4];
    const int* etyp = (const int*)d_in[5];
    // float inputs (fp32 or bf16 — detected on device)
    const void* ent_tab = d_in[6];
    const void* rtab_in = d_in[7];
    const void* bases_in = d_in[8];
    const void* coeffs_in = d_in[9];
    const void* wsl_in = d_in[10];
    const void* bsl_in = d_in[11];
    const void* gamma_in = d_in[12];
    const void* beta_in = d_in[13];

    // workspace layout (~206 MB)
    char* ws = (char*)d_ws;
    size_t off = 0;
    auto alloc = [&](size_t bytes) -> char* {
        char* p = ws + off;
        off += (bytes + 511) & ~(size_t)511;
        return p;
    };
    int* flag            = (int*)alloc(4);
    float* deg           = (float*)alloc((size_t)N_ENTS * 4);
    float* outb          = (float*)alloc((size_t)N_ENTS * DIM * 4);
    unsigned short* z    = (unsigned short*)alloc((size_t)N_ENTS * 512 * 2);
    unsigned short* entb = (unsigned short*)alloc((size_t)N_ENTS * DIM * 2);  // converted x / layer-2 out
    unsigned short* xA   = (unsigned short*)alloc((size_t)N_ENTS * DIM * 2);  // layer-1 out
    unsigned short* par  = (unsigned short*)alloc((size_t)P_TOTAL * 2);
    float* hr            = (float*)alloc((size_t)BATCH * DIM * 4);
    float* stats         = (float*)alloc(2 * 2 * DIM * 4);
    (void)ws_size; (void)in_sizes; (void)n_in; (void)out_size;

    const int* src = eidx;
    const int* dst = eidx + NEDGE;

    // 1) detect float dtype of inputs (writes flag; graph-safe, no host sync)
    k_detect<<<1, 256, 0, stream>>>((const unsigned int*)ent_tab, flag);

    // 2) canonicalize all float inputs to bf16 in workspace
    auto conv = [&](const void* s, unsigned short* d, int n) {
        k_conv<<<(n + 255) / 256, 256, 0, stream>>>(s, d, n, flag);
    };
    conv(ent_tab,   entb,           N_ENTS * DIM);
    conv(rtab_in,   par + P_REL,    N_RELS * DIM);
    conv(bases_in,  par + P_BASES,  2 * NB * DIM * DIM);
    conv(coeffs_in, par + P_COEFF,  2 * N_RELS * NB);
    conv(wsl_in,    par + P_WSL,    2 * DIM * DIM);
    conv(bsl_in,    par + P_BSL,    2 * DIM);
    conv(gamma_in,  par + P_GAMMA,  2 * DIM);
    conv(beta_in,   par + P_BETA,   2 * DIM);

    hipMemsetAsync(deg, 0, (size_t)N_ENTS * 4, stream);
    hipMemsetAsync(stats, 0, 2 * 2 * DIM * 4, stream);
    k_deg<<<(NEDGE + 255) / 256, 256, 0, stream>>>(dst, deg);

    const unsigned short* xin = entb;
    unsigned short* bufs[2] = {xA, entb};  // layer-2 output overwrites entb
    for (int l = 0; l < 2; ++l) {
        const unsigned short* wl = par + P_WSL   + l * DIM * DIM;
        const unsigned short* bl = par + P_BSL   + l * DIM;
        const unsigned short* bs = par + P_BASES + l * NB * DIM * DIM;
        const unsigned short* cf = par + P_COEFF + l * N_RELS * NB;
        const unsigned short* gm = par + P_GAMMA + l * DIM;
        const unsigned short* bt = par + P_BETA  + l * DIM;
        float* st = stats + l * 2 * DIM;

        k_node_gemm<<<N_ENTS / 4, 256, 0, stream>>>(xin, wl, bl, bs, outb, z);
        k_edge<<<NEDGE / 4, 256, 0, stream>>>(src, dst, etyp, cf, z, outb);
        k_finstats<<<(N_ENTS + 127) / 128, 256, 0, stream>>>(outb, deg, st);
        k_bn<<<(N_ENTS * 64) / 256, 256, 0, stream>>>(outb, st, gm, bt, bufs[l]);
        xin = bufs[l];
    }

    const unsigned short* ent = entb;  // final embeddings
    k_hr<<<BATCH / 4, 256, 0, stream>>>(head, rel, ent, par + P_REL, hr);
    k_score<<<BATCH / 4, 256, 0, stream>>>(tail, hr, ent, d_out, flag, 0, 0);
    k_score<<<(BATCH * NNEG) / 4, 256, 0, stream>>>(negi, hr, ent, d_out, flag, BATCH, 6);
}

// Round 3
// 615.266 us; speedup vs baseline: 3.8106x; 3.8106x over previous
//
#include <hip/hip_runtime.h>
#include <stdint.h>

// Problem constants
#define N_ENTS  100000
#define M_PAD   100096          // 782 * 128
#define N_RELS  16
#define DIM     128
#define NB      4
#define KTOT    640             // 128 (self) + 4*128 (bases)
#define NEDGE   640000
#define BATCH   1024
#define NNEG    64
#define BN_EPS  1e-5f

// converted-parameter buffer layout (ushort offsets)
#define P_REL    0        // [16][128]
#define P_BASES  2048     // [2][4][128][128]
#define P_COEFF  133120   // [2][16][4]
#define P_WSL    133248   // [2][128][128]
#define P_BSL    166016   // [2][128]
#define P_GAMMA  166272   // [2][128]
#define P_BETA   166528   // [2][128]
#define P_TOTAL  166784

typedef unsigned int uint;
typedef short short8 __attribute__((ext_vector_type(8)));
typedef float f4 __attribute__((ext_vector_type(4)));

// bf16 helpers (internal canonical format = raw ushort bf16)
__device__ __forceinline__ float bf2f(unsigned short u) {
    return __uint_as_float(((unsigned int)u) << 16);
}
__device__ __forceinline__ float bflo(unsigned int u) { return __uint_as_float(u << 16); }
__device__ __forceinline__ float bfhi(unsigned int u) { return __uint_as_float(u & 0xffff0000u); }
__device__ __forceinline__ unsigned short f2bf(float f) {
    unsigned int x = __float_as_uint(f);
    x += 0x7fffu + ((x >> 16) & 1u);
    return (unsigned short)(x >> 16);
}
__device__ __forceinline__ unsigned int pack2(float a, float b) {
    return (unsigned int)f2bf(a) | ((unsigned int)f2bf(b) << 16);
}

// ---------------- dtype detection (fp32 vs bf16 storage) ----------------
__device__ __forceinline__ int bf16_like(unsigned int h) {
    unsigned int m = h & 0x7FFFu;
    return (m == 0u) || (m >= 0x2D00u && m < 0x4400u);
}
__global__ __launch_bounds__(256) void k_detect(const unsigned int* __restrict__ ent,
                                                int* __restrict__ flag) {
    __shared__ int cnt[256];
    unsigned int u = ent[threadIdx.x];
    cnt[threadIdx.x] = bf16_like(u & 0xFFFFu) & bf16_like(u >> 16);
    __syncthreads();
    for (int s = 128; s > 0; s >>= 1) {
        if (threadIdx.x < s) cnt[threadIdx.x] += cnt[threadIdx.x + s];
        __syncthreads();
    }
    if (threadIdx.x == 0) flag[0] = (cnt[0] >= 140) ? 1 : 0;
}

// ---------------- converts ----------------
__global__ __launch_bounds__(256) void k_conv(const void* __restrict__ src,
                                              unsigned short* __restrict__ dst,
                                              int n, const int* __restrict__ flag) {
    const int i = blockIdx.x * 256 + threadIdx.x;
    if (i >= n) return;
    dst[i] = flag[0] ? ((const unsigned short*)src)[i] : f2bf(((const float*)src)[i]);
}
// entity -> xy rows (stride KTOT), cols [0,128)
__global__ __launch_bounds__(256) void k_conv_x(const void* __restrict__ src,
                                                unsigned short* __restrict__ xy,
                                                const int* __restrict__ flag) {
    const int i = blockIdx.x * 256 + threadIdx.x;   // grid exact: N_ENTS*DIM/256
    const int n = i >> 7, d = i & 127;
    const unsigned short v = flag[0] ? ((const unsigned short*)src)[i]
                                     : f2bf(((const float*)src)[i]);
    xy[(size_t)n * KTOT + d] = v;
}

// ---------------- CSR build (counting sort by dst) ----------------
__global__ __launch_bounds__(256) void k_count(const int* __restrict__ dst, int* __restrict__ cnt) {
    int e = blockIdx.x * 256 + threadIdx.x;
    if (e < NEDGE) atomicAdd(&cnt[dst[e]], 1);
}
__global__ __launch_bounds__(256) void k_bsum(const int* __restrict__ cnt, int* __restrict__ bsum) {
    __shared__ int l[256];
    int i = blockIdx.x * 256 + threadIdx.x;
    l[threadIdx.x] = (i < N_ENTS) ? cnt[i] : 0;
    __syncthreads();
    for (int s = 128; s > 0; s >>= 1) {
        if (threadIdx.x < s) l[threadIdx.x] += l[threadIdx.x + s];
        __syncthreads();
    }
    if (threadIdx.x == 0) bsum[blockIdx.x] = l[0];
}
__global__ __launch_bounds__(512) void k_scan1(int* __restrict__ bsum) {  // 391 partials
    __shared__ int tmp[512];
    const int t = threadIdx.x;
    const int v = (t < 391) ? bsum[t] : 0;
    tmp[t] = v;
    __syncthreads();
    for (int off = 1; off < 512; off <<= 1) {
        int u = (t >= off) ? tmp[t - off] : 0;
        __syncthreads();
        tmp[t] += u;
        __syncthreads();
    }
    if (t < 391) bsum[t] = tmp[t] - v;   // exclusive
}
__global__ __launch_bounds__(256) void k_starts(const int* __restrict__ cnt,
                                                const int* __restrict__ boff,
                                                int* __restrict__ starts) {
    __shared__ int tmp[256];
    const int t = threadIdx.x;
    const int i = blockIdx.x * 256 + t;
    const int v = (i < N_ENTS) ? cnt[i] : 0;
    tmp[t] = v;
    __syncthreads();
    for (int off = 1; off < 256; off <<= 1) {
        int u = (t >= off) ? tmp[t - off] : 0;
        __syncthreads();
        tmp[t] += u;
        __syncthreads();
    }
    if (i < N_ENTS) starts[i] = tmp[t] - v + boff[blockIdx.x];
}
__global__ __launch_bounds__(256) void k_fill(const int* __restrict__ src, const int* __restrict__ dst,
                                              const int* __restrict__ et, const int* __restrict__ starts,
                                              int* __restrict__ cur, uint* __restrict__ ebuf) {
    int e = blockIdx.x * 256 + threadIdx.x;
    if (e >= NEDGE) return;
    const int d = dst[e];
    const int p = atomicAdd(&cur[d], 1);
    ebuf[starts[d] + p] = (uint)src[e] | ((uint)et[e] << 20);
}

// ---------------- edge aggregation (gather, no atomics) ----------------
// y_b[n] = sum_{e in in(n)} coeff[et,b] * x[src];  writes xy cols [128,640) as bf16
__global__ __launch_bounds__(256) void k_agg(
    const uint* __restrict__ ebuf, const int* __restrict__ starts, const int* __restrict__ cnt,
    const unsigned short* __restrict__ coeffs /* [16][4] layer slice */,
    unsigned short* __restrict__ xy)
{
    const int wave = threadIdx.x >> 6, lane = threadIdx.x & 63;
    const int n = blockIdx.x * 4 + wave;   // grid exact: N_ENTS/4
    const int c0 = starts[n], cn = cnt[n];
    float ylo[NB] = {0, 0, 0, 0}, yhi[NB] = {0, 0, 0, 0};
    const uint* __restrict__ x32 = (const uint*)xy;
    for (int i = 0; i < cn; ++i) {
        const uint rec = ebuf[c0 + i];
        const uint s = rec & 0xFFFFFu, r = rec >> 20;
        const uint2 cc = *(const uint2*)(coeffs + r * 4);
        const float cb[NB] = {bflo(cc.x), bfhi(cc.x), bflo(cc.y), bfhi(cc.y)};
        const uint xw = x32[(size_t)s * (KTOT / 2) + lane];
        const float xl = bflo(xw), xh = bfhi(xw);
#pragma unroll
        for (int b = 0; b < NB; ++b) {
            ylo[b] = fmaf(cb[b], xl, ylo[b]);
            yhi[b] = fmaf(cb[b], xh, yhi[b]);
        }
    }
    uint* xyw = (uint*)xy;
#pragma unroll
    for (int b = 0; b < NB; ++b)
        xyw[(size_t)n * (KTOT / 2) + 64 + b * 64 + lane] = pack2(ylo[b], yhi[b]);
}

// ---------------- build Wt[n=128][k=640] = [w_sl ; bases0..3]^T ----------------
__global__ __launch_bounds__(256) void k_transw(const unsigned short* __restrict__ wsl,
                                                const unsigned short* __restrict__ bases,
                                                unsigned short* __restrict__ Wt) {
    const int i = blockIdx.x * 256 + threadIdx.x;   // grid exact: 640*128/256 = 320
    const int k = i >> 7, n = i & 127;
    const unsigned short v = (k < DIM) ? wsl[k * DIM + n] : bases[(k - DIM) * DIM + n];
    Wt[n * KTOT + k] = v;
}

// ---------------- MFMA GEMM + fused deg-div, bias, BN-stats ----------------
// C[M_PAD x 128] = xy[M_PAD x 640] @ Wt^T ; block = 128x128 tile, 4 waves (2x2 of 64x64)
__global__ __launch_bounds__(256) void k_gemm(
    const unsigned short* __restrict__ xy, const unsigned short* __restrict__ Wt,
    const unsigned short* __restrict__ bsl, const int* __restrict__ cnt,
    float* __restrict__ out, float* __restrict__ st)
{
    __shared__ __align__(16) unsigned short sa[8192];  // A frags [chunk(16)][lane(64)][8]
    __shared__ __align__(16) unsigned short sb[8192];  // B frags
    const int tid = threadIdx.x;
    const int wave = tid >> 6, lane = tid & 63;
    const int quad = lane >> 4, l16 = lane & 15;
    const int m0 = blockIdx.x * 128;
    const int wrt0 = (wave >> 1) * 4;   // wave row-tile base
    const int wct0 = (wave & 1) * 4;    // wave col-tile base

    f4 acc[4][4];
#pragma unroll
    for (int i = 0; i < 4; ++i)
#pragma unroll
        for (int j = 0; j < 4; ++j)
#pragma unroll
            for (int r = 0; r < 4; ++r) acc[i][j][r] = 0.f;

    for (int kc = 0; kc < KTOT / 64; ++kc) {
        const int kbase = kc * 64;
        __syncthreads();
#pragma unroll
        for (int i = 0; i < 4; ++i) {
            const int c = wave * 4 + i;            // 16 fragment-chunks
            const int t = c >> 1, ks = c & 1;      // t = tile idx, ks = 32-k step
            const int k = kbase + ks * 32 + quad * 8;
            const uint4 va = *(const uint4*)(xy + (size_t)(m0 + t * 16 + l16) * KTOT + k);
            *(uint4*)(sa + (size_t)(c * 64 + lane) * 8) = va;
            const uint4 vb = *(const uint4*)(Wt + (size_t)(t * 16 + l16) * KTOT + k);
            *(uint4*)(sb + (size_t)(c * 64 + lane) * 8) = vb;
        }
        __syncthreads();
#pragma unroll
        for (int ks = 0; ks < 2; ++ks) {
            short8 av[4], bv[4];
#pragma unroll
            for (int i = 0; i < 4; ++i) {
                av[i] = *(const short8*)(sa + (size_t)(((wrt0 + i) * 2 + ks) * 64 + lane) * 8);
                bv[i] = *(const short8*)(sb + (size_t)(((wct0 + i) * 2 + ks) * 64 + lane) * 8);
            }
#pragma unroll
            for (int i = 0; i < 4; ++i)
#pragma unroll
                for (int j = 0; j < 4; ++j)
                    acc[i][j] = __builtin_amdgcn_mfma_f32_16x16x32_bf16(av[i], bv[j], acc[i][j], 0, 0, 0);
        }
    }

    // epilogue: o = (acc + bias)/deg ; store fp32 ; accumulate BN stats
    float s_sum[4] = {0, 0, 0, 0}, s_ssq[4] = {0, 0, 0, 0};
#pragma unroll
    for (int i = 0; i < 4; ++i) {
#pragma unroll
        for (int r = 0; r < 4; ++r) {
            const int row = m0 + (wrt0 + i) * 16 + quad * 4 + r;   // C/D: row = quad*4+reg
            const int rc = row < N_ENTS ? row : N_ENTS - 1;
            const float rdeg = 1.0f / fmaxf((float)cnt[rc], 1.0f);
            const bool valid = row < N_ENTS;
#pragma unroll
            for (int j = 0; j < 4; ++j) {
                const int f = (wct0 + j) * 16 + l16;               // C/D: col = lane&15
                const float o = (acc[i][j][r] + bf2f(bsl[f])) * rdeg;
                if (valid) {
                    out[(size_t)row * DIM + f] = o;
                    s_sum[j] += o;
                    s_ssq[j] += o * o;
                }
            }
        }
    }
#pragma unroll
    for (int j = 0; j < 4; ++j) {
        float s = s_sum[j], q = s_ssq[j];
        s += __shfl_xor(s, 16, 64); s += __shfl_xor(s, 32, 64);
        q += __shfl_xor(q, 16, 64); q += __shfl_xor(q, 32, 64);
        if (quad == 0) {
            const int f = (wct0 + j) * 16 + l16;
            atomicAdd(&st[f], s);
            atomicAdd(&st[DIM + f], q);
        }
    }
}

// ---------------- BN apply + ReLU -> bf16 x cols of xy ----------------
__global__ __launch_bounds__(256) void k_bn(
    const float* __restrict__ out, const float* __restrict__ st,
    const unsigned short* __restrict__ gamma, const unsigned short* __restrict__ beta,
    unsigned short* __restrict__ xy)
{
    const long long i = (long long)blockIdx.x * 256 + threadIdx.x;  // pair idx; grid exact N*64/256
    const int p = (int)(i & 63);
    const long long n = i >> 6;
    const int f0 = p * 2;
    const float inv_n = 1.0f / (float)N_ENTS;
    const float mu0 = st[f0] * inv_n, mu1 = st[f0 + 1] * inv_n;
    const float v0 = st[DIM + f0] * inv_n - mu0 * mu0;
    const float v1 = st[DIM + f0 + 1] * inv_n - mu1 * mu1;
    const float g0 = bf2f(gamma[f0]) * rsqrtf(v0 + BN_EPS);
    const float g1 = bf2f(gamma[f0 + 1]) * rsqrtf(v1 + BN_EPS);
    const float2 o = *(const float2*)(out + i * 2);
    float r0 = fmaxf((o.x - mu0) * g0 + bf2f(beta[f0]), 0.f);
    float r1 = fmaxf((o.y - mu1) * g1 + bf2f(beta[f0 + 1]), 0.f);
    ((uint*)xy)[n * (KTOT / 2) + p] = pack2(r0, r1);
}

// ---------------- scoring ----------------
__global__ __launch_bounds__(256) void k_hr(
    const int* __restrict__ head, const int* __restrict__ rel,
    const unsigned short* __restrict__ xy, const unsigned short* __restrict__ rtab,
    float* __restrict__ hr)
{
    const int wave = threadIdx.x >> 6, lane = threadIdx.x & 63;
    const int i = blockIdx.x * 4 + wave;
    const int h = head[i], r = rel[i];
    const uint hv = ((const uint*)xy)[(size_t)h * (KTOT / 2) + lane];
    const uint rv = ((const uint*)(rtab))[(size_t)r * 64 + lane];
    float2 o;
    o.x = bflo(hv) + bflo(rv);
    o.y = bfhi(hv) + bfhi(rv);
    *(float2*)(hr + (size_t)i * DIM + 2 * lane) = o;
}

__global__ __launch_bounds__(256) void k_score(
    const int* __restrict__ idx, const float* __restrict__ hr,
    const unsigned short* __restrict__ xy, void* __restrict__ outp,
    const int* __restrict__ flag, int obase, int hr_shift)
{
    const int wave = threadIdx.x >> 6, lane = threadIdx.x & 63;
    const int w = blockIdx.x * 4 + wave;
    const int i = w >> hr_shift;
    const int t = idx[w];
    const float2 h = *(const float2*)(hr + (size_t)i * DIM + 2 * lane);
    const uint tv = ((const uint*)xy)[(size_t)t * (KTOT / 2) + lane];
    const float d0 = h.x - bflo(tv), d1 = h.y - bfhi(tv);
    float s = d0 * d0 + d1 * d1;
#pragma unroll
    for (int m = 32; m >= 1; m >>= 1) s += __shfl_xor(s, m, 64);
    if (lane == 0) {
        const float v = -sqrtf(s);
        if (flag[0]) ((unsigned short*)outp)[obase + w] = f2bf(v);
        else         ((float*)outp)[obase + w] = v;
    }
}

extern "C" void kernel_launch(void* const* d_in, const int* in_sizes, int n_in,
                              void* d_out, int out_size, void* d_ws, size_t ws_size,
                              hipStream_t stream)
{
    const int* head = (const int*)d_in[0];
    const int* rel  = (const int*)d_in[1];
    const int* tail = (const int*)d_in[2];
    const int* negi = (const int*)d_in[3];
    const int* eidx = (const int*)d_in[4];
    const int* etyp = (const int*)d_in[5];
    const void* ent_tab = d_in[6];
    const void* rtab_in = d_in[7];
    const void* bases_in = d_in[8];
    const void* coeffs_in = d_in[9];
    const void* wsl_in = d_in[10];
    const void* bsl_in = d_in[11];
    const void* gamma_in = d_in[12];
    const void* beta_in = d_in[13];

    char* ws = (char*)d_ws;
    size_t off = 0;
    auto alloc = [&](size_t bytes) -> char* {
        char* p = ws + off;
        off += (bytes + 511) & ~(size_t)511;
        return p;
    };
    int* flag            = (int*)alloc(4);
    int* cnt             = (int*)alloc((size_t)N_ENTS * 4);
    int* starts          = (int*)alloc((size_t)N_ENTS * 4);
    int* bsum            = (int*)alloc(391 * 4);
    int* cur             = (int*)alloc((size_t)N_ENTS * 4);
    uint* ebuf           = (uint*)alloc((size_t)NEDGE * 4);
    unsigned short* xy   = (unsigned short*)alloc((size_t)M_PAD * KTOT * 2);   // 128.1 MB
    float* outb          = (float*)alloc((size_t)N_ENTS * DIM * 4);            // 51.2 MB
    unsigned short* par  = (unsigned short*)alloc((size_t)P_TOTAL * 2);
    unsigned short* Wt   = (unsigned short*)alloc((size_t)DIM * KTOT * 2);
    float* hr            = (float*)alloc((size_t)BATCH * DIM * 4);
    float* stats         = (float*)alloc(2 * 2 * DIM * 4);
    (void)ws_size; (void)in_sizes; (void)n_in; (void)out_size;

    const int* esrc = eidx;
    const int* edst = eidx + NEDGE;

    k_detect<<<1, 256, 0, stream>>>((const unsigned int*)ent_tab, flag);

    auto conv = [&](const void* s, unsigned short* d, int n) {
        k_conv<<<(n + 255) / 256, 256, 0, stream>>>(s, d, n, flag);
    };
    k_conv_x<<<N_ENTS * DIM / 256, 256, 0, stream>>>(ent_tab, xy, flag);
    conv(rtab_in,   par + P_REL,    N_RELS * DIM);
    conv(bases_in,  par + P_BASES,  2 * NB * DIM * DIM);
    conv(coeffs_in, par + P_COEFF,  2 * N_RELS * NB);
    conv(wsl_in,    par + P_WSL,    2 * DIM * DIM);
    conv(bsl_in,    par + P_BSL,    2 * DIM);
    conv(gamma_in,  par + P_GAMMA,  2 * DIM);
    conv(beta_in,   par + P_BETA,   2 * DIM);

    hipMemsetAsync(cnt, 0, (size_t)N_ENTS * 4, stream);
    hipMemsetAsync(cur, 0, (size_t)N_ENTS * 4, stream);
    hipMemsetAsync(stats, 0, 2 * 2 * DIM * 4, stream);

    // CSR build
    k_count<<<NEDGE / 256, 256, 0, stream>>>(edst, cnt);
    k_bsum<<<391, 256, 0, stream>>>(cnt, bsum);
    k_scan1<<<1, 512, 0, stream>>>(bsum);
    k_starts<<<391, 256, 0, stream>>>(cnt, bsum, starts);
    k_fill<<<NEDGE / 256, 256, 0, stream>>>(esrc, edst, etyp, starts, cur, ebuf);

    for (int l = 0; l < 2; ++l) {
        const unsigned short* wl = par + P_WSL   + l * DIM * DIM;
        const unsigned short* bl = par + P_BSL   + l * DIM;
        const unsigned short* bs = par + P_BASES + l * NB * DIM * DIM;
        const unsigned short* cf = par + P_COEFF + l * N_RELS * NB;
        const unsigned short* gm = par + P_GAMMA + l * DIM;
        const unsigned short* bt = par + P_BETA  + l * DIM;
        float* st = stats + l * 2 * DIM;

        k_agg<<<N_ENTS / 4, 256, 0, stream>>>(ebuf, starts, cnt, cf, xy);
        k_transw<<<KTOT * DIM / 256, 256, 0, stream>>>(wl, bs, Wt);
        k_gemm<<<M_PAD / 128, 256, 0, stream>>>(xy, Wt, bl, cnt, outb, st);
        k_bn<<<N_ENTS * 64 / 256, 256, 0, stream>>>(outb, st, gm, bt, xy);
    }

    k_hr<<<BATCH / 4, 256, 0, stream>>>(head, rel, xy, par + P_REL, hr);
    k_score<<<BATCH / 4, 256, 0, stream>>>(tail, hr, xy, d_out, flag, 0, 0);
    k_score<<<(BATCH * NNEG) / 4, 256, 0, stream>>>(negi, hr, xy, d_out, flag, BATCH, 6);
}

// Round 4
// 591.999 us; speedup vs baseline: 3.9603x; 1.0393x over previous
//
#include <hip/hip_runtime.h>
#include <stdint.h>

// Problem constants
#define N_ENTS  100000
#define M_PAD   100096          // 782 * 128
#define N_RELS  16
#define DIM     128
#define NB      4
#define KTOT    640             // 128 (self) + 4*128 (bases)
#define NEDGE   640000
#define BATCH   1024
#define NNEG    64
#define BN_EPS  1e-5f

// converted-parameter buffer layout (ushort offsets)
#define P_REL    0        // [16][128]
#define P_BASES  2048     // [2][4][128][128]
#define P_COEFF  133120   // [2][16][4]
#define P_WSL    133248   // [2][128][128]
#define P_BSL    166016   // [2][128]
#define P_GAMMA  166272   // [2][128]
#define P_BETA   166528   // [2][128]
#define P_TOTAL  166784

typedef unsigned int uint;
typedef short short8 __attribute__((ext_vector_type(8)));
typedef float f4 __attribute__((ext_vector_type(4)));

// bf16 helpers (internal canonical format = raw ushort bf16)
__device__ __forceinline__ float bf2f(unsigned short u) {
    return __uint_as_float(((unsigned int)u) << 16);
}
__device__ __forceinline__ float bflo(unsigned int u) { return __uint_as_float(u << 16); }
__device__ __forceinline__ float bfhi(unsigned int u) { return __uint_as_float(u & 0xffff0000u); }
__device__ __forceinline__ unsigned short f2bf(float f) {
    unsigned int x = __float_as_uint(f);
    x += 0x7fffu + ((x >> 16) & 1u);
    return (unsigned short)(x >> 16);
}
__device__ __forceinline__ unsigned int pack2(float a, float b) {
    return (unsigned int)f2bf(a) | ((unsigned int)f2bf(b) << 16);
}

// async global->LDS, 16B per lane; LDS dest = uniform base + lane*16
__device__ __forceinline__ void gl_lds16(const unsigned short* g, unsigned short* l) {
    __builtin_amdgcn_global_load_lds(
        (__attribute__((address_space(1))) void*)g,
        (__attribute__((address_space(3))) void*)l,
        16, 0, 0);
}

// ---------------- dtype detection (fp32 vs bf16 storage) ----------------
__device__ __forceinline__ int bf16_like(unsigned int h) {
    unsigned int m = h & 0x7FFFu;
    return (m == 0u) || (m >= 0x2D00u && m < 0x4400u);
}
__global__ __launch_bounds__(256) void k_detect(const unsigned int* __restrict__ ent,
                                                int* __restrict__ flag) {
    __shared__ int cnt[256];
    unsigned int u = ent[threadIdx.x];
    cnt[threadIdx.x] = bf16_like(u & 0xFFFFu) & bf16_like(u >> 16);
    __syncthreads();
    for (int s = 128; s > 0; s >>= 1) {
        if (threadIdx.x < s) cnt[threadIdx.x] += cnt[threadIdx.x + s];
        __syncthreads();
    }
    if (threadIdx.x == 0) flag[0] = (cnt[0] >= 140) ? 1 : 0;
}

// ---------------- converts ----------------
__global__ __launch_bounds__(256) void k_conv(const void* __restrict__ src,
                                              unsigned short* __restrict__ dst,
                                              int n, const int* __restrict__ flag) {
    const int i = blockIdx.x * 256 + threadIdx.x;
    if (i >= n) return;
    dst[i] = flag[0] ? ((const unsigned short*)src)[i] : f2bf(((const float*)src)[i]);
}
// entity -> xy rows (stride KTOT), cols [0,128)
__global__ __launch_bounds__(256) void k_conv_x(const void* __restrict__ src,
                                                unsigned short* __restrict__ xy,
                                                const int* __restrict__ flag) {
    const int i = blockIdx.x * 256 + threadIdx.x;   // grid exact: N_ENTS*DIM/256
    const int n = i >> 7, d = i & 127;
    const unsigned short v = flag[0] ? ((const unsigned short*)src)[i]
                                     : f2bf(((const float*)src)[i]);
    xy[(size_t)n * KTOT + d] = v;
}

// ---------------- CSR build (counting sort by dst) ----------------
__global__ __launch_bounds__(256) void k_count(const int* __restrict__ dst, int* __restrict__ cnt) {
    int e = blockIdx.x * 256 + threadIdx.x;
    if (e < NEDGE) atomicAdd(&cnt[dst[e]], 1);
}
__global__ __launch_bounds__(256) void k_bsum(const int* __restrict__ cnt, int* __restrict__ bsum) {
    __shared__ int l[256];
    int i = blockIdx.x * 256 + threadIdx.x;
    l[threadIdx.x] = (i < N_ENTS) ? cnt[i] : 0;
    __syncthreads();
    for (int s = 128; s > 0; s >>= 1) {
        if (threadIdx.x < s) l[threadIdx.x] += l[threadIdx.x + s];
        __syncthreads();
    }
    if (threadIdx.x == 0) bsum[blockIdx.x] = l[0];
}
__global__ __launch_bounds__(512) void k_scan1(int* __restrict__ bsum) {  // 391 partials
    __shared__ int tmp[512];
    const int t = threadIdx.x;
    const int v = (t < 391) ? bsum[t] : 0;
    tmp[t] = v;
    __syncthreads();
    for (int off = 1; off < 512; off <<= 1) {
        int u = (t >= off) ? tmp[t - off] : 0;
        __syncthreads();
        tmp[t] += u;
        __syncthreads();
    }
    if (t < 391) bsum[t] = tmp[t] - v;   // exclusive
}
__global__ __launch_bounds__(256) void k_starts(const int* __restrict__ cnt,
                                                const int* __restrict__ boff,
                                                int* __restrict__ starts) {
    __shared__ int tmp[256];
    const int t = threadIdx.x;
    const int i = blockIdx.x * 256 + t;
    const int v = (i < N_ENTS) ? cnt[i] : 0;
    tmp[t] = v;
    __syncthreads();
    for (int off = 1; off < 256; off <<= 1) {
        int u = (t >= off) ? tmp[t - off] : 0;
        __syncthreads();
        tmp[t] += u;
        __syncthreads();
    }
    if (i < N_ENTS) starts[i] = tmp[t] - v + boff[blockIdx.x];
}
__global__ __launch_bounds__(256) void k_fill(const int* __restrict__ src, const int* __restrict__ dst,
                                              const int* __restrict__ et, const int* __restrict__ starts,
                                              int* __restrict__ cur, uint* __restrict__ ebuf) {
    int e = blockIdx.x * 256 + threadIdx.x;
    if (e >= NEDGE) return;
    const int d = dst[e];
    const int p = atomicAdd(&cur[d], 1);
    ebuf[starts[d] + p] = (uint)src[e] | ((uint)et[e] << 20);
}

// ---------------- edge aggregation (gather, no atomics, 2-stream ILP) ----------------
// y_b[n] = sum_{e in in(n)} coeff[et,b] * x[src];  writes xy cols [128,640) as bf16
__global__ __launch_bounds__(256) void k_agg(
    const uint* __restrict__ ebuf, const int* __restrict__ starts, const int* __restrict__ cnt,
    const unsigned short* __restrict__ coeffs /* [16][4] layer slice */,
    unsigned short* __restrict__ xy)
{
    __shared__ uint2 scf[16];
    if (threadIdx.x < 16) scf[threadIdx.x] = *(const uint2*)(coeffs + threadIdx.x * 4);
    __syncthreads();
    const int wave = threadIdx.x >> 6, lane = threadIdx.x & 63;
    const int n = blockIdx.x * 4 + wave;   // grid exact: N_ENTS/4
    const int c0 = starts[n], cn = cnt[n];
    const int h = (cn + 1) >> 1;
    float alo[NB] = {0, 0, 0, 0}, ahi[NB] = {0, 0, 0, 0};
    float blo[NB] = {0, 0, 0, 0}, bhi[NB] = {0, 0, 0, 0};
    const uint* __restrict__ x32 = (const uint*)xy;
    for (int i = 0; i < h; ++i) {
        const uint recA = ebuf[c0 + i];
        const int hasB = (h + i) < cn;
        const uint recB = hasB ? ebuf[c0 + h + i] : recA;
        const uint sA = recA & 0xFFFFFu, rA = recA >> 20;
        const uint sB = recB & 0xFFFFFu, rB = recB >> 20;
        const uint xwA = x32[(size_t)sA * (KTOT / 2) + lane];   // independent
        const uint xwB = x32[(size_t)sB * (KTOT / 2) + lane];   // streams
        const uint2 ccA = scf[rA];
        const uint2 ccB = scf[rB];
        const float xlA = bflo(xwA), xhA = bfhi(xwA);
        const float cA[NB] = {bflo(ccA.x), bfhi(ccA.x), bflo(ccA.y), bfhi(ccA.y)};
#pragma unroll
        for (int b = 0; b < NB; ++b) {
            alo[b] = fmaf(cA[b], xlA, alo[b]);
            ahi[b] = fmaf(cA[b], xhA, ahi[b]);
        }
        if (hasB) {
            const float xlB = bflo(xwB), xhB = bfhi(xwB);
            const float cB[NB] = {bflo(ccB.x), bfhi(ccB.x), bflo(ccB.y), bfhi(ccB.y)};
#pragma unroll
            for (int b = 0; b < NB; ++b) {
                blo[b] = fmaf(cB[b], xlB, blo[b]);
                bhi[b] = fmaf(cB[b], xhB, bhi[b]);
            }
        }
    }
    uint* xyw = (uint*)xy;
#pragma unroll
    for (int b = 0; b < NB; ++b)
        xyw[(size_t)n * (KTOT / 2) + 64 + b * 64 + lane] = pack2(alo[b] + blo[b], ahi[b] + bhi[b]);
}

// ---------------- build Wt[n=128][k=640] = [w_sl ; bases0..3]^T ----------------
__global__ __launch_bounds__(256) void k_transw(const unsigned short* __restrict__ wsl,
                                                const unsigned short* __restrict__ bases,
                                                unsigned short* __restrict__ Wt) {
    const int i = blockIdx.x * 256 + threadIdx.x;   // grid exact: 640*128/256 = 320
    const int k = i >> 7, n = i & 127;
    const unsigned short v = (k < DIM) ? wsl[k * DIM + n] : bases[(k - DIM) * DIM + n];
    Wt[n * KTOT + k] = v;
}

// ---------------- MFMA GEMM (async LDS staging) + fused deg-div, bias, BN-stats ----------------
// C[M_PAD x 128] = xy[M_PAD x 640] @ Wt^T ; block = 128x128 tile, 4 waves (2x2 of 64x64)
__global__ __launch_bounds__(256) void k_gemm(
    const unsigned short* __restrict__ xy, const unsigned short* __restrict__ Wt,
    const unsigned short* __restrict__ bsl, const int* __restrict__ cnt,
    float* __restrict__ out, float* __restrict__ st)
{
    __shared__ __align__(16) unsigned short sa[8192];  // A frags [chunk(16)][lane(64)][8]
    __shared__ __align__(16) unsigned short sb[8192];  // B frags
    const int tid = threadIdx.x;
    const int wave = tid >> 6, lane = tid & 63;
    const int quad = lane >> 4, l16 = lane & 15;
    const int m0 = blockIdx.x * 128;
    const int wrt0 = (wave >> 1) * 4;   // wave row-tile base
    const int wct0 = (wave & 1) * 4;    // wave col-tile base

    // staging pointers: chunk c = wave*4+i; t = c>>1 (16-row tile), ks = c&1 (32-k step)
    const unsigned short* gA[4];
    const unsigned short* gB[4];
    unsigned short* lA[4];
    unsigned short* lB[4];
#pragma unroll
    for (int i = 0; i < 4; ++i) {
        const int c = wave * 4 + i;
        const int t = c >> 1, ks = c & 1;
        gA[i] = xy + (size_t)(m0 + t * 16 + l16) * KTOT + ks * 32 + quad * 8;
        gB[i] = Wt + (size_t)(t * 16 + l16) * KTOT + ks * 32 + quad * 8;
        lA[i] = sa + (size_t)c * 512;   // byte base c*1024; HW adds lane*16
        lB[i] = sb + (size_t)c * 512;
    }

    f4 acc[4][4];
#pragma unroll
    for (int i = 0; i < 4; ++i)
#pragma unroll
        for (int j = 0; j < 4; ++j)
#pragma unroll
            for (int r = 0; r < 4; ++r) acc[i][j][r] = 0.f;

    for (int kc = 0; kc < KTOT / 64; ++kc) {
        __syncthreads();   // LDS free (all reads of previous chunk done)
#pragma unroll
        for (int i = 0; i < 4; ++i) {
            gl_lds16(gA[i], lA[i]);
            gl_lds16(gB[i], lB[i]);
            gA[i] += 64;
            gB[i] += 64;
        }
        __syncthreads();   // drains vmcnt -> LDS ready
#pragma unroll
        for (int ks = 0; ks < 2; ++ks) {
            short8 av[4], bv[4];
#pragma unroll
            for (int i = 0; i < 4; ++i) {
                av[i] = *(const short8*)(sa + (size_t)(((wrt0 + i) * 2 + ks) * 64 + lane) * 8);
                bv[i] = *(const short8*)(sb + (size_t)(((wct0 + i) * 2 + ks) * 64 + lane) * 8);
            }
#pragma unroll
            for (int i = 0; i < 4; ++i)
#pragma unroll
                for (int j = 0; j < 4; ++j)
                    acc[i][j] = __builtin_amdgcn_mfma_f32_16x16x32_bf16(av[i], bv[j], acc[i][j], 0, 0, 0);
        }
    }

    // epilogue: o = (acc + bias)/deg ; store fp32 ; accumulate BN stats
    float s_sum[4] = {0, 0, 0, 0}, s_ssq[4] = {0, 0, 0, 0};
#pragma unroll
    for (int i = 0; i < 4; ++i) {
#pragma unroll
        for (int r = 0; r < 4; ++r) {
            const int row = m0 + (wrt0 + i) * 16 + quad * 4 + r;   // C/D: row = quad*4+reg
            const int rc = row < N_ENTS ? row : N_ENTS - 1;
            const float rdeg = 1.0f / fmaxf((float)cnt[rc], 1.0f);
            const bool valid = row < N_ENTS;
#pragma unroll
            for (int j = 0; j < 4; ++j) {
                const int f = (wct0 + j) * 16 + l16;               // C/D: col = lane&15
                const float o = (acc[i][j][r] + bf2f(bsl[f])) * rdeg;
                if (valid) {
                    out[(size_t)row * DIM + f] = o;
                    s_sum[j] += o;
                    s_ssq[j] += o * o;
                }
            }
        }
    }
#pragma unroll
    for (int j = 0; j < 4; ++j) {
        float s = s_sum[j], q = s_ssq[j];
        s += __shfl_xor(s, 16, 64); s += __shfl_xor(s, 32, 64);
        q += __shfl_xor(q, 16, 64); q += __shfl_xor(q, 32, 64);
        if (quad == 0) {
            const int f = (wct0 + j) * 16 + l16;
            atomicAdd(&st[f], s);
            atomicAdd(&st[DIM + f], q);
        }
    }
}

// ---------------- BN apply + ReLU -> bf16 x cols of xy ----------------
__global__ __launch_bounds__(256) void k_bn(
    const float* __restrict__ out, const float* __restrict__ st,
    const unsigned short* __restrict__ gamma, const unsigned short* __restrict__ beta,
    unsigned short* __restrict__ xy)
{
    const long long i = (long long)blockIdx.x * 256 + threadIdx.x;  // pair idx; grid exact N*64/256
    const int p = (int)(i & 63);
    const long long n = i >> 6;
    const int f0 = p * 2;
    const float inv_n = 1.0f / (float)N_ENTS;
    const float mu0 = st[f0] * inv_n, mu1 = st[f0 + 1] * inv_n;
    const float v0 = st[DIM + f0] * inv_n - mu0 * mu0;
    const float v1 = st[DIM + f0 + 1] * inv_n - mu1 * mu1;
    const float g0 = bf2f(gamma[f0]) * rsqrtf(v0 + BN_EPS);
    const float g1 = bf2f(gamma[f0 + 1]) * rsqrtf(v1 + BN_EPS);
    const float2 o = *(const float2*)(out + i * 2);
    float r0 = fmaxf((o.x - mu0) * g0 + bf2f(beta[f0]), 0.f);
    float r1 = fmaxf((o.y - mu1) * g1 + bf2f(beta[f0 + 1]), 0.f);
    ((uint*)xy)[n * (KTOT / 2) + p] = pack2(r0, r1);
}

// ---------------- scoring ----------------
__global__ __launch_bounds__(256) void k_hr(
    const int* __restrict__ head, const int* __restrict__ rel,
    const unsigned short* __restrict__ xy, const unsigned short* __restrict__ rtab,
    float* __restrict__ hr)
{
    const int wave = threadIdx.x >> 6, lane = threadIdx.x & 63;
    const int i = blockIdx.x * 4 + wave;
    const int h = head[i], r = rel[i];
    const uint hv = ((const uint*)xy)[(size_t)h * (KTOT / 2) + lane];
    const uint rv = ((const uint*)(rtab))[(size_t)r * 64 + lane];
    float2 o;
    o.x = bflo(hv) + bflo(rv);
    o.y = bfhi(hv) + bfhi(rv);
    *(float2*)(hr + (size_t)i * DIM + 2 * lane) = o;
}

__global__ __launch_bounds__(256) void k_score(
    const int* __restrict__ idx, const float* __restrict__ hr,
    const unsigned short* __restrict__ xy, void* __restrict__ outp,
    const int* __restrict__ flag, int obase, int hr_shift)
{
    const int wave = threadIdx.x >> 6, lane = threadIdx.x & 63;
    const int w = blockIdx.x * 4 + wave;
    const int i = w >> hr_shift;
    const int t = idx[w];
    const float2 h = *(const float2*)(hr + (size_t)i * DIM + 2 * lane);
    const uint tv = ((const uint*)xy)[(size_t)t * (KTOT / 2) + lane];
    const float d0 = h.x - bflo(tv), d1 = h.y - bfhi(tv);
    float s = d0 * d0 + d1 * d1;
#pragma unroll
    for (int m = 32; m >= 1; m >>= 1) s += __shfl_xor(s, m, 64);
    if (lane == 0) {
        const float v = -sqrtf(s);
        if (flag[0]) ((unsigned short*)outp)[obase + w] = f2bf(v);
        else         ((float*)outp)[obase + w] = v;
    }
}

extern "C" void kernel_launch(void* const* d_in, const int* in_sizes, int n_in,
                              void* d_out, int out_size, void* d_ws, size_t ws_size,
                              hipStream_t stream)
{
    const int* head = (const int*)d_in[0];
    const int* rel  = (const int*)d_in[1];
    const int* tail = (const int*)d_in[2];
    const int* negi = (const int*)d_in[3];
    const int* eidx = (const int*)d_in[4];
    const int* etyp = (const int*)d_in[5];
    const void* ent_tab = d_in[6];
    const void* rtab_in = d_in[7];
    const void* bases_in = d_in[8];
    const void* coeffs_in = d_in[9];
    const void* wsl_in = d_in[10];
    const void* bsl_in = d_in[11];
    const void* gamma_in = d_in[12];
    const void* beta_in = d_in[13];

    char* ws = (char*)d_ws;
    size_t off = 0;
    auto alloc = [&](size_t bytes) -> char* {
        char* p = ws + off;
        off += (bytes + 511) & ~(size_t)511;
        return p;
    };
    int* flag            = (int*)alloc(4);
    int* cnt             = (int*)alloc((size_t)N_ENTS * 4);
    int* starts          = (int*)alloc((size_t)N_ENTS * 4);
    int* bsum            = (int*)alloc(391 * 4);
    int* cur             = (int*)alloc((size_t)N_ENTS * 4);
    uint* ebuf           = (uint*)alloc((size_t)NEDGE * 4);
    unsigned short* xy   = (unsigned short*)alloc((size_t)M_PAD * KTOT * 2);   // 128.1 MB
    float* outb          = (float*)alloc((size_t)N_ENTS * DIM * 4);            // 51.2 MB
    unsigned short* par  = (unsigned short*)alloc((size_t)P_TOTAL * 2);
    unsigned short* Wt   = (unsigned short*)alloc((size_t)DIM * KTOT * 2);
    float* hr            = (float*)alloc((size_t)BATCH * DIM * 4);
    float* stats         = (float*)alloc(2 * 2 * DIM * 4);
    (void)ws_size; (void)in_sizes; (void)n_in; (void)out_size;

    const int* esrc = eidx;
    const int* edst = eidx + NEDGE;

    k_detect<<<1, 256, 0, stream>>>((const unsigned int*)ent_tab, flag);

    auto conv = [&](const void* s, unsigned short* d, int n) {
        k_conv<<<(n + 255) / 256, 256, 0, stream>>>(s, d, n, flag);
    };
    k_conv_x<<<N_ENTS * DIM / 256, 256, 0, stream>>>(ent_tab, xy, flag);
    conv(rtab_in,   par + P_REL,    N_RELS * DIM);
    conv(bases_in,  par + P_BASES,  2 * NB * DIM * DIM);
    conv(coeffs_in, par + P_COEFF,  2 * N_RELS * NB);
    conv(wsl_in,    par + P_WSL,    2 * DIM * DIM);
    conv(bsl_in,    par + P_BSL,    2 * DIM);
    conv(gamma_in,  par + P_GAMMA,  2 * DIM);
    conv(beta_in,   par + P_BETA,   2 * DIM);

    hipMemsetAsync(cnt, 0, (size_t)N_ENTS * 4, stream);
    hipMemsetAsync(cur, 0, (size_t)N_ENTS * 4, stream);
    hipMemsetAsync(stats, 0, 2 * 2 * DIM * 4, stream);

    // CSR build
    k_count<<<NEDGE / 256, 256, 0, stream>>>(edst, cnt);
    k_bsum<<<391, 256, 0, stream>>>(cnt, bsum);
    k_scan1<<<1, 512, 0, stream>>>(bsum);
    k_starts<<<391, 256, 0, stream>>>(cnt, bsum, starts);
    k_fill<<<NEDGE / 256, 256, 0, stream>>>(esrc, edst, etyp, starts, cur, ebuf);

    for (int l = 0; l < 2; ++l) {
        const unsigned short* wl = par + P_WSL   + l * DIM * DIM;
        const unsigned short* bl = par + P_BSL   + l * DIM;
        const unsigned short* bs = par + P_BASES + l * NB * DIM * DIM;
        const unsigned short* cf = par + P_COEFF + l * N_RELS * NB;
        const unsigned short* gm = par + P_GAMMA + l * DIM;
        const unsigned short* bt = par + P_BETA  + l * DIM;
        float* st = stats + l * 2 * DIM;

        k_agg<<<N_ENTS / 4, 256, 0, stream>>>(ebuf, starts, cnt, cf, xy);
        k_transw<<<KTOT * DIM / 256, 256, 0, stream>>>(wl, bs, Wt);
        k_gemm<<<M_PAD / 128, 256, 0, stream>>>(xy, Wt, bl, cnt, outb, st);
        k_bn<<<N_ENTS * 64 / 256, 256, 0, stream>>>(outb, st, gm, bt, xy);
    }

    k_hr<<<BATCH / 4, 256, 0, stream>>>(head, rel, xy, par + P_REL, hr);
    k_score<<<BATCH / 4, 256, 0, stream>>>(tail, hr, xy, d_out, flag, 0, 0);
    k_score<<<(BATCH * NNEG) / 4, 256, 0, stream>>>(negi, hr, xy, d_out, flag, BATCH, 6);
}

// Round 6
// 547.176 us; speedup vs baseline: 4.2847x; 1.0819x over previous
//
#include <hip/hip_runtime.h>
#include <stdint.h>

// Problem constants
#define N_ENTS  100000
#define M_PAD   100096          // 782 * 128
#define N_RELS  16
#define DIM     128
#define NB      4
#define KTOT    640             // 128 (self) + 4*128 (bases)
#define NEDGE   640000
#define BATCH   1024
#define NNEG    64
#define BN_EPS  1e-5f
#define NBLK    782             // M_PAD/128

// converted-parameter buffer layout (ushort offsets)
#define P_REL    0        // [16][128]
#define P_BASES  2048     // [2][4][128][128]
#define P_COEFF  133120   // [2][16][4]
#define P_WSL    133248   // [2][128][128]
#define P_BSL    166016   // [2][128]
#define P_GAMMA  166272   // [2][128]
#define P_BETA   166528   // [2][128]
#define P_TOTAL  166784

typedef unsigned int uint;
typedef short short8 __attribute__((ext_vector_type(8)));
typedef float f4 __attribute__((ext_vector_type(4)));

// bf16 helpers
__device__ __forceinline__ float bf2f(unsigned short u) {
    return __uint_as_float(((unsigned int)u) << 16);
}
__device__ __forceinline__ float bflo(unsigned int u) { return __uint_as_float(u << 16); }
__device__ __forceinline__ float bfhi(unsigned int u) { return __uint_as_float(u & 0xffff0000u); }
__device__ __forceinline__ unsigned short f2bf(float f) {
    unsigned int x = __float_as_uint(f);
    x += 0x7fffu + ((x >> 16) & 1u);
    return (unsigned short)(x >> 16);
}
__device__ __forceinline__ unsigned int pack2(float a, float b) {
    return (unsigned int)f2bf(a) | ((unsigned int)f2bf(b) << 16);
}

// ---------------- dtype detection (fp32 vs bf16 storage) ----------------
__device__ __forceinline__ int bf16_like(unsigned int h) {
    unsigned int m = h & 0x7FFFu;
    return (m == 0u) || (m >= 0x2D00u && m < 0x4400u);
}
__global__ __launch_bounds__(256) void k_detect(const unsigned int* __restrict__ ent,
                                                int* __restrict__ flag) {
    __shared__ int cnt[256];
    unsigned int u = ent[threadIdx.x];
    cnt[threadIdx.x] = bf16_like(u & 0xFFFFu) & bf16_like(u >> 16);
    __syncthreads();
    for (int s = 128; s > 0; s >>= 1) {
        if (threadIdx.x < s) cnt[threadIdx.x] += cnt[threadIdx.x + s];
        __syncthreads();
    }
    if (threadIdx.x == 0) flag[0] = (cnt[0] >= 140) ? 1 : 0;
}

// ---------------- converts ----------------
__device__ __forceinline__ unsigned short cvt1(const void* src, int i, int isbf) {
    return isbf ? ((const unsigned short*)src)[i] : f2bf(((const float*)src)[i]);
}
// all small params -> par[], one dispatch
__global__ __launch_bounds__(256) void k_conv_params(
    const void* __restrict__ rtab, const void* __restrict__ bases,
    const void* __restrict__ coeffs, const void* __restrict__ wsl,
    const void* __restrict__ bsl, const void* __restrict__ gamma,
    const void* __restrict__ beta,
    unsigned short* __restrict__ par, const int* __restrict__ flag)
{
    const int i = blockIdx.x * 256 + threadIdx.x;
    if (i >= P_TOTAL) return;
    const int isbf = flag[0];
    unsigned short v;
    if      (i < P_BASES)  v = cvt1(rtab,   i - P_REL,    isbf);
    else if (i < P_COEFF)  v = cvt1(bases,  i - P_BASES,  isbf);
    else if (i < P_WSL)    v = cvt1(coeffs, i - P_COEFF,  isbf);
    else if (i < P_BSL)    v = cvt1(wsl,    i - P_WSL,    isbf);
    else if (i < P_GAMMA)  v = cvt1(bsl,    i - P_BSL,    isbf);
    else if (i < P_BETA)   v = cvt1(gamma,  i - P_GAMMA,  isbf);
    else                   v = cvt1(beta,   i - P_BETA,   isbf);
    par[i] = v;
}
// entity -> xy rows (stride KTOT), cols [0,128), 4 elems/thread
__global__ __launch_bounds__(256) void k_conv_x(const void* __restrict__ src,
                                                unsigned short* __restrict__ xy,
                                                const int* __restrict__ flag) {
    const int i4 = blockIdx.x * 256 + threadIdx.x;   // grid exact: N_ENTS*DIM/4/256
    const int i = i4 * 4;
    const int n = i >> 7, d = i & 127;
    uint2 w;
    if (flag[0]) {
        w = *(const uint2*)((const unsigned short*)src + i);
    } else {
        const float4 f = *(const float4*)((const float*)src + i);
        w.x = pack2(f.x, f.y);
        w.y = pack2(f.z, f.w);
    }
    *(uint2*)(xy + (size_t)n * KTOT + d) = w;
}

// ---------------- CSR build (counting sort by dst) ----------------
__global__ __launch_bounds__(256) void k_count(const int* __restrict__ dst, int* __restrict__ cnt) {
    int e = blockIdx.x * 256 + threadIdx.x;
    if (e < NEDGE) atomicAdd(&cnt[dst[e]], 1);
}
__global__ __launch_bounds__(256) void k_bsum(const int* __restrict__ cnt, int* __restrict__ bsum) {
    __shared__ int l[256];
    int i = blockIdx.x * 256 + threadIdx.x;
    l[threadIdx.x] = (i < N_ENTS) ? cnt[i] : 0;
    __syncthreads();
    for (int s = 128; s > 0; s >>= 1) {
        if (threadIdx.x < s) l[threadIdx.x] += l[threadIdx.x + s];
        __syncthreads();
    }
    if (threadIdx.x == 0) bsum[blockIdx.x] = l[0];
}
__global__ __launch_bounds__(512) void k_scan1(int* __restrict__ bsum) {  // 391 partials
    __shared__ int tmp[512];
    const int t = threadIdx.x;
    const int v = (t < 391) ? bsum[t] : 0;
    tmp[t] = v;
    __syncthreads();
    for (int off = 1; off < 512; off <<= 1) {
        int u = (t >= off) ? tmp[t - off] : 0;
        __syncthreads();
        tmp[t] += u;
        __syncthreads();
    }
    if (t < 391) bsum[t] = tmp[t] - v;   // exclusive
}
__global__ __launch_bounds__(256) void k_starts(const int* __restrict__ cnt,
                                                const int* __restrict__ boff,
                                                int* __restrict__ starts) {
    __shared__ int tmp[256];
    const int t = threadIdx.x;
    const int i = blockIdx.x * 256 + t;
    const int v = (i < N_ENTS) ? cnt[i] : 0;
    tmp[t] = v;
    __syncthreads();
    for (int off = 1; off < 256; off <<= 1) {
        int u = (t >= off) ? tmp[t - off] : 0;
        __syncthreads();
        tmp[t] += u;
        __syncthreads();
    }
    if (i < N_ENTS) starts[i] = tmp[t] - v + boff[blockIdx.x];
}
__global__ __launch_bounds__(256) void k_fill(const int* __restrict__ src, const int* __restrict__ dst,
                                              const int* __restrict__ et, const int* __restrict__ starts,
                                              int* __restrict__ cur, uint* __restrict__ ebuf) {
    int e = blockIdx.x * 256 + threadIdx.x;
    if (e >= NEDGE) return;
    const int d = dst[e];
    const int p = atomicAdd(&cur[d], 1);
    ebuf[starts[d] + p] = (uint)src[e] | ((uint)et[e] << 20);
}

// ---------------- edge aggregation (gather, no atomics, 4-stream ILP) ----------------
__global__ __launch_bounds__(256) void k_agg(
    const uint* __restrict__ ebuf, const int* __restrict__ starts, const int* __restrict__ cnt,
    const unsigned short* __restrict__ coeffs /* [16][4] layer slice */,
    unsigned short* __restrict__ xy)
{
    __shared__ uint2 scf[16];
    if (threadIdx.x < 16) scf[threadIdx.x] = *(const uint2*)(coeffs + threadIdx.x * 4);
    __syncthreads();
    const int wave = threadIdx.x >> 6, lane = threadIdx.x & 63;
    const int n = blockIdx.x * 4 + wave;   // grid exact: N_ENTS/4
    const int c0 = starts[n], cn = cnt[n];
    const int q = (cn + 3) >> 2;
    float lo[4][NB] = {}, hi[4][NB] = {};
    const uint* __restrict__ x32 = (const uint*)xy;
    for (int i = 0; i < q; ++i) {
        uint rec[4];
        int valid[4];
#pragma unroll
        for (int s = 0; s < 4; ++s) {
            const int p = s * q + i;
            valid[s] = p < cn;
            rec[s] = ebuf[c0 + (valid[s] ? p : 0)];
        }
        uint xw[4];
#pragma unroll
        for (int s = 0; s < 4; ++s)
            xw[s] = x32[(size_t)(rec[s] & 0xFFFFFu) * (KTOT / 2) + lane];
#pragma unroll
        for (int s = 0; s < 4; ++s) {
            uint2 cc = scf[rec[s] >> 20];
            if (!valid[s]) { cc.x = 0; cc.y = 0; }
            const float cb[NB] = {bflo(cc.x), bfhi(cc.x), bflo(cc.y), bfhi(cc.y)};
            const float xl = bflo(xw[s]), xh = bfhi(xw[s]);
#pragma unroll
            for (int b = 0; b < NB; ++b) {
                lo[s][b] = fmaf(cb[b], xl, lo[s][b]);
                hi[s][b] = fmaf(cb[b], xh, hi[s][b]);
            }
        }
    }
    uint* xyw = (uint*)xy;
#pragma unroll
    for (int b = 0; b < NB; ++b) {
        const float l = (lo[0][b] + lo[1][b]) + (lo[2][b] + lo[3][b]);
        const float h = (hi[0][b] + hi[1][b]) + (hi[2][b] + hi[3][b]);
        xyw[(size_t)n * (KTOT / 2) + 64 + b * 64 + lane] = pack2(l, h);
    }
}

// ---------------- build Wt for BOTH layers: Wt[l][n=128][k=640] ----------------
__global__ __launch_bounds__(256) void k_transw2(const unsigned short* __restrict__ par,
                                                 unsigned short* __restrict__ Wt) {
    const int i = blockIdx.x * 256 + threadIdx.x;   // grid exact: 2*640*128/256 = 640
    const int l = i / (KTOT * DIM);                  // 81920 elements per layer (FIX: was i>>16)
    const int rem = i - l * (KTOT * DIM);
    const int k = rem >> 7, n = rem & 127;
    const unsigned short v = (k < DIM)
        ? par[P_WSL + l * DIM * DIM + k * DIM + n]
        : par[P_BASES + l * NB * DIM * DIM + (k - DIM) * DIM + n];
    Wt[(size_t)l * DIM * KTOT + n * KTOT + k] = v;
}

// ---------------- barrier-free MFMA GEMM + fused deg-div, bias, block BN-stats ----------------
// C[M_PAD x 128] = xy[M_PAD x 640] @ Wt^T ; 4 waves = 2x2 of 64x64, all frags global->reg
__global__ __launch_bounds__(256, 2) void k_gemm(
    const unsigned short* __restrict__ xy, const unsigned short* __restrict__ Wt,
    const unsigned short* __restrict__ bsl, const int* __restrict__ cnt,
    float* __restrict__ out, float* __restrict__ pstats)
{
    const int tid = threadIdx.x;
    const int wave = tid >> 6, lane = tid & 63;
    const int quad = lane >> 4, l16 = lane & 15;
    const int m0 = blockIdx.x * 128;
    const int rbase = (wave >> 1) * 64;   // wave row offset in tile
    const int col0 = (wave & 1) * 64;     // wave col offset

    // fragment load bases (A-operand: lane holds A[m=l16][k=quad*8+j])
    const unsigned short* pa = xy + (size_t)(m0 + rbase + l16) * KTOT + quad * 8;
    const unsigned short* pb = Wt + (size_t)(col0 + l16) * KTOT + quad * 8;

    f4 acc[4][4];
#pragma unroll
    for (int i = 0; i < 4; ++i)
#pragma unroll
        for (int j = 0; j < 4; ++j)
#pragma unroll
            for (int r = 0; r < 4; ++r) acc[i][j][r] = 0.f;

#pragma unroll 2
    for (int kc = 0; kc < KTOT / 64; ++kc) {
#pragma unroll
        for (int ks = 0; ks < 2; ++ks) {
            short8 av[4], bv[4];
#pragma unroll
            for (int i = 0; i < 4; ++i)
                av[i] = *(const short8*)(pa + (size_t)i * 16 * KTOT + kc * 64 + ks * 32);
#pragma unroll
            for (int j = 0; j < 4; ++j)
                bv[j] = *(const short8*)(pb + (size_t)j * 16 * KTOT + kc * 64 + ks * 32);
#pragma unroll
            for (int i = 0; i < 4; ++i)
#pragma unroll
                for (int j = 0; j < 4; ++j)
                    acc[i][j] = __builtin_amdgcn_mfma_f32_16x16x32_bf16(av[i], bv[j], acc[i][j], 0, 0, 0);
        }
    }

    // epilogue: o = (acc + bias)/deg ; store fp32 ; block-local BN stats (no global atomics)
    float s_sum[4] = {0, 0, 0, 0}, s_ssq[4] = {0, 0, 0, 0};
#pragma unroll
    for (int i = 0; i < 4; ++i) {
#pragma unroll
        for (int r = 0; r < 4; ++r) {
            const int row = m0 + rbase + i * 16 + quad * 4 + r;    // C/D: row = quad*4+reg
            const int rc = row < N_ENTS ? row : N_ENTS - 1;
            const float rdeg = 1.0f / fmaxf((float)cnt[rc], 1.0f);
            const bool valid = row < N_ENTS;
#pragma unroll
            for (int j = 0; j < 4; ++j) {
                const int f = col0 + j * 16 + l16;                 // C/D: col = lane&15
                const float o = (acc[i][j][r] + bf2f(bsl[f])) * rdeg;
                if (valid) {
                    out[(size_t)row * DIM + f] = o;
                    s_sum[j] += o;
                    s_ssq[j] += o * o;
                }
            }
        }
    }
    __shared__ float ssum[4][64], sssq[4][64];
#pragma unroll
    for (int j = 0; j < 4; ++j) {
        float s = s_sum[j], q = s_ssq[j];
        s += __shfl_xor(s, 16, 64); s += __shfl_xor(s, 32, 64);
        q += __shfl_xor(q, 16, 64); q += __shfl_xor(q, 32, 64);
        if (quad == 0) {
            ssum[wave][j * 16 + l16] = s;
            sssq[wave][j * 16 + l16] = q;
        }
    }
    __syncthreads();
    // pstats[blk][0..127]=sum per f, [128..255]=ssq per f
    {
        const int f = tid & 127;
        const int g = f >> 6;         // col group: waves {g, g+2}
        const int fl = f & 63;
        const float v = (tid < 128) ? (ssum[g][fl] + ssum[g + 2][fl])
                                    : (sssq[g][fl] + sssq[g + 2][fl]);
        pstats[(size_t)blockIdx.x * 256 + tid] = v;
    }
}

// ---------------- reduce per-block stats -> st[256] ----------------
__global__ __launch_bounds__(256) void k_stats(const float* __restrict__ pstats,
                                               float* __restrict__ st) {
    const int o = threadIdx.x;
    const int b0 = blockIdx.x * 49;           // 16 blocks * 49 >= 782
    float s = 0.f;
    for (int b = b0; b < b0 + 49 && b < NBLK; ++b)
        s += pstats[(size_t)b * 256 + o];
    atomicAdd(&st[o], s);
}

// ---------------- BN apply + ReLU -> bf16 x cols of xy (4 elems/thread) ----------------
__global__ __launch_bounds__(256) void k_bn(
    const float* __restrict__ out, const float* __restrict__ st,
    const unsigned short* __restrict__ gamma, const unsigned short* __restrict__ beta,
    unsigned short* __restrict__ xy)
{
    const int i4 = blockIdx.x * 256 + threadIdx.x;   // grid exact: N_ENTS*DIM/4/256
    const int f0 = (i4 & 31) * 4;
    const int n = i4 >> 5;
    const float inv_n = 1.0f / (float)N_ENTS;
    const float4 o = *(const float4*)(out + (size_t)i4 * 4);
    float r[4] = {o.x, o.y, o.z, o.w};
#pragma unroll
    for (int e = 0; e < 4; ++e) {
        const int f = f0 + e;
        const float mu = st[f] * inv_n;
        const float var = st[DIM + f] * inv_n - mu * mu;
        const float g = bf2f(gamma[f]) * rsqrtf(var + BN_EPS);
        r[e] = fmaxf((r[e] - mu) * g + bf2f(beta[f]), 0.f);
    }
    uint2 w;
    w.x = pack2(r[0], r[1]);
    w.y = pack2(r[2], r[3]);
    *(uint2*)(xy + (size_t)n * KTOT + f0) = w;
}

// ---------------- scoring ----------------
__global__ __launch_bounds__(256) void k_hr(
    const int* __restrict__ head, const int* __restrict__ rel,
    const unsigned short* __restrict__ xy, const unsigned short* __restrict__ rtab,
    float* __restrict__ hr)
{
    const int wave = threadIdx.x >> 6, lane = threadIdx.x & 63;
    const int i = blockIdx.x * 4 + wave;
    const int h = head[i], r = rel[i];
    const uint hv = ((const uint*)xy)[(size_t)h * (KTOT / 2) + lane];
    const uint rv = ((const uint*)(rtab))[(size_t)r * 64 + lane];
    float2 o;
    o.x = bflo(hv) + bflo(rv);
    o.y = bfhi(hv) + bfhi(rv);
    *(float2*)(hr + (size_t)i * DIM + 2 * lane) = o;
}

// fused pos+neg scoring: w<BATCH -> pos(tail), else neg
__global__ __launch_bounds__(256) void k_score(
    const int* __restrict__ tail, const int* __restrict__ negi,
    const float* __restrict__ hr, const unsigned short* __restrict__ xy,
    void* __restrict__ outp, const int* __restrict__ flag)
{
    const int wave = threadIdx.x >> 6, lane = threadIdx.x & 63;
    const int w = blockIdx.x * 4 + wave;   // grid exact: (BATCH + BATCH*NNEG)/4
    int i, t, o;
    if (w < BATCH) { i = w; t = tail[w]; o = w; }
    else { const int w2 = w - BATCH; i = w2 >> 6; t = negi[w2]; o = w; }
    const float2 h = *(const float2*)(hr + (size_t)i * DIM + 2 * lane);
    const uint tv = ((const uint*)xy)[(size_t)t * (KTOT / 2) + lane];
    const float d0 = h.x - bflo(tv), d1 = h.y - bfhi(tv);
    float s = d0 * d0 + d1 * d1;
#pragma unroll
    for (int m = 32; m >= 1; m >>= 1) s += __shfl_xor(s, m, 64);
    if (lane == 0) {
        const float v = -sqrtf(s);
        if (flag[0]) ((unsigned short*)outp)[o] = f2bf(v);
        else         ((float*)outp)[o] = v;
    }
}

extern "C" void kernel_launch(void* const* d_in, const int* in_sizes, int n_in,
                              void* d_out, int out_size, void* d_ws, size_t ws_size,
                              hipStream_t stream)
{
    const int* head = (const int*)d_in[0];
    const int* rel  = (const int*)d_in[1];
    const int* tail = (const int*)d_in[2];
    const int* negi = (const int*)d_in[3];
    const int* eidx = (const int*)d_in[4];
    const int* etyp = (const int*)d_in[5];
    const void* ent_tab = d_in[6];
    const void* rtab_in = d_in[7];
    const void* bases_in = d_in[8];
    const void* coeffs_in = d_in[9];
    const void* wsl_in = d_in[10];
    const void* bsl_in = d_in[11];
    const void* gamma_in = d_in[12];
    const void* beta_in = d_in[13];

    char* ws = (char*)d_ws;
    size_t off = 0;
    auto alloc = [&](size_t bytes) -> char* {
        char* p = ws + off;
        off += (bytes + 511) & ~(size_t)511;
        return p;
    };
    int* flag            = (int*)alloc(4);
    int* cnt             = (int*)alloc((size_t)N_ENTS * 4);
    int* starts          = (int*)alloc((size_t)N_ENTS * 4);
    int* bsum            = (int*)alloc(391 * 4);
    int* cur             = (int*)alloc((size_t)N_ENTS * 4);
    uint* ebuf           = (uint*)alloc((size_t)NEDGE * 4);
    unsigned short* xy   = (unsigned short*)alloc((size_t)M_PAD * KTOT * 2);   // 128.1 MB
    float* outb          = (float*)alloc((size_t)N_ENTS * DIM * 4);            // 51.2 MB
    unsigned short* par  = (unsigned short*)alloc((size_t)P_TOTAL * 2);
    unsigned short* Wt   = (unsigned short*)alloc((size_t)2 * DIM * KTOT * 2); // both layers
    float* pstats        = (float*)alloc((size_t)NBLK * 256 * 4);              // 800 KB
    float* hr            = (float*)alloc((size_t)BATCH * DIM * 4);
    float* stats         = (float*)alloc(2 * 2 * DIM * 4);
    (void)ws_size; (void)in_sizes; (void)n_in; (void)out_size;

    const int* esrc = eidx;
    const int* edst = eidx + NEDGE;

    k_detect<<<1, 256, 0, stream>>>((const unsigned int*)ent_tab, flag);

    k_conv_x<<<N_ENTS * DIM / 4 / 256, 256, 0, stream>>>(ent_tab, xy, flag);
    k_conv_params<<<(P_TOTAL + 255) / 256, 256, 0, stream>>>(
        rtab_in, bases_in, coeffs_in, wsl_in, bsl_in, gamma_in, beta_in, par, flag);
    k_transw2<<<2 * KTOT * DIM / 256, 256, 0, stream>>>(par, Wt);

    hipMemsetAsync(cnt, 0, (size_t)N_ENTS * 4, stream);
    hipMemsetAsync(cur, 0, (size_t)N_ENTS * 4, stream);
    hipMemsetAsync(stats, 0, 2 * 2 * DIM * 4, stream);

    // CSR build
    k_count<<<NEDGE / 256, 256, 0, stream>>>(edst, cnt);
    k_bsum<<<391, 256, 0, stream>>>(cnt, bsum);
    k_scan1<<<1, 512, 0, stream>>>(bsum);
    k_starts<<<391, 256, 0, stream>>>(cnt, bsum, starts);
    k_fill<<<NEDGE / 256, 256, 0, stream>>>(esrc, edst, etyp, starts, cur, ebuf);

    for (int l = 0; l < 2; ++l) {
        const unsigned short* bl = par + P_BSL   + l * DIM;
        const unsigned short* cf = par + P_COEFF + l * N_RELS * NB;
        const unsigned short* gm = par + P_GAMMA + l * DIM;
        const unsigned short* bt = par + P_BETA  + l * DIM;
        const unsigned short* wt = Wt + (size_t)l * DIM * KTOT;
        float* st = stats + l * 2 * DIM;

        k_agg<<<N_ENTS / 4, 256, 0, stream>>>(ebuf, starts, cnt, cf, xy);
        k_gemm<<<NBLK, 256, 0, stream>>>(xy, wt, bl, cnt, outb, pstats);
        k_stats<<<16, 256, 0, stream>>>(pstats, st);
        k_bn<<<N_ENTS * DIM / 4 / 256, 256, 0, stream>>>(outb, st, gm, bt, xy);
    }

    k_hr<<<BATCH / 4, 256, 0, stream>>>(head, rel, xy, par + P_REL, hr);
    k_score<<<(BATCH + BATCH * NNEG) / 4, 256, 0, stream>>>(tail, negi, hr, xy, d_out, flag);
}